// Round 16
// baseline (391.848 us; speedup 1.0000x reference)
//
#include <hip/hip_runtime.h>

#define BATCH 16
#define CHN   512
#define INTER 64
#define NPIX  2304   // 48*48

typedef _Float16 f16;
typedef _Float16 f16x8 __attribute__((ext_vector_type(8)));
typedef _Float16 f16x4 __attribute__((ext_vector_type(4)));
typedef short    s16x8 __attribute__((ext_vector_type(8)));
typedef float    f32x16 __attribute__((ext_vector_type(16)));

// workspace byte offsets (total 85,590,016 B)
#define XT_OFF   ((size_t)0)          // xT f16  [b][n][c]   16*2304*512
#define QT_OFF   ((size_t)37748736)   // qT f16  [b][n][64]  (pre-scaled by log2e)
#define KT_OFF   ((size_t)42467328)   // kT f16  [b][n][64]
#define VB_OFF   ((size_t)47185920)   // v  bf16 [b][c][m]   16*512*2304
#define WHQ_OFF  ((size_t)84934656)   // Wq f16  [64][512]
#define WHK_OFF  ((size_t)85000192)   // Wk f16  [64][512]
#define WHV_OFF  ((size_t)85065728)   // Wv f16  [512][512]

#define LOG2E 1.4426950408889634f

__device__ inline unsigned short f2bf(float f) {
    unsigned int u = __float_as_uint(f);
    unsigned int r = (u + 0x7FFFu + ((u >> 16) & 1u)) >> 16;
    return (unsigned short)r;
}

// pack two fp32 -> (bf16(a) | bf16(b)<<16), round-half-up via +0x8000 then
// v_perm. HW-PROVEN in v6/v8 (351.8 us run). v12's v_cvt_pk_bf16_f32 swap
// FAILED correctness (absmax 8.05) — its gfx950 packing semantics differ
// from assumed; do NOT reintroduce without isolated HW verification.
__device__ inline unsigned pack_bf16(float a, float b) {
    unsigned ua = __float_as_uint(a) + 0x8000u;
    unsigned ub = __float_as_uint(b) + 0x8000u;
    return __builtin_amdgcn_perm(ub, ua, 0x07060302u);
}

// pack two fp32 -> two f16 in one u32
__device__ inline unsigned pack_f16(float a, float b) {
    f16 ha = (f16)a, hb = (f16)b;
    unsigned short ua = *(unsigned short*)&ha, ub = *(unsigned short*)&hb;
    return (unsigned)ua | ((unsigned)ub << 16);
}

// 2^x via v_exp_f32
__device__ inline float exp2_fast(float x) {
#if __has_builtin(__builtin_amdgcn_exp2f)
    return __builtin_amdgcn_exp2f(x);
#else
    float r; asm("v_exp_f32 %0, %1" : "=v"(r) : "v"(x)); return r;
#endif
}

// async global->LDS, 16 B per lane; lane l lands at base + l*16.
__device__ inline void gload_lds16(const void* g, void* l) {
    __builtin_amdgcn_global_load_lds(
        (const __attribute__((address_space(1))) void*)g,
        (__attribute__((address_space(3))) void*)l, 16, 0, 0);
}

// Lane-half swap between two VGPRs (HW-verified).
__device__ inline void swap32(unsigned x, unsigned y, unsigned& nx, unsigned& ny, int lh) {
#if __has_builtin(__builtin_amdgcn_permlane32_swap)
    auto r = __builtin_amdgcn_permlane32_swap(x, y, false, false);
    nx = r[0]; ny = r[1];
#else
    const unsigned xs = (unsigned)__shfl_xor((int)x, 32, 64);
    const unsigned ys = (unsigned)__shfl_xor((int)y, 32, 64);
    nx = lh ? ys : x;
    ny = lh ? y  : xs;
#endif
}

// ---------------------------------------------------------------------------
// x [b][c][n] fp32  ->  xT [b][n][c] f16   (64x64 LDS tile transpose)
// ---------------------------------------------------------------------------
__global__ __launch_bounds__(256) void convert_x_kernel(
    const float* __restrict__ x, f16* __restrict__ xT)
{
    const int n0 = blockIdx.x * 64;
    const int c0 = blockIdx.y * 64;
    const int b  = blockIdx.z;
    const int t  = threadIdx.x;

    __shared__ float tile[64][65];

    {
        const int cr   = t >> 2;
        const int ncol = (t & 3) * 16;
        const float* src = x + ((size_t)b * CHN + (size_t)(c0 + cr)) * NPIX + n0 + ncol;
        #pragma unroll
        for (int u = 0; u < 4; ++u) {
            const float4 v4 = *(const float4*)(src + u * 4);
            tile[cr][ncol + u * 4 + 0] = v4.x;
            tile[cr][ncol + u * 4 + 1] = v4.y;
            tile[cr][ncol + u * 4 + 2] = v4.z;
            tile[cr][ncol + u * 4 + 3] = v4.w;
        }
    }
    __syncthreads();
    #pragma unroll
    for (int r = 0; r < 2; ++r) {
        const int id = t + r * 256;
        const int n  = id >> 3;
        const int cg = id & 7;
        f16x8 o;
        #pragma unroll
        for (int j = 0; j < 8; ++j) o[j] = (f16)tile[cg * 8 + j][n];
        *(f16x8*)(xT + ((size_t)b * NPIX + (size_t)(n0 + n)) * CHN + c0 + cg * 8) = o;
    }
}

// ---------------------------------------------------------------------------
// W fp32 -> f16. grid (256, 3), block 256.
// ---------------------------------------------------------------------------
__global__ __launch_bounds__(256) void convert_w_kernel(
    const float* __restrict__ Wq, const float* __restrict__ Wk,
    const float* __restrict__ Wv, f16* __restrict__ whq,
    f16* __restrict__ whk, f16* __restrict__ whv)
{
    const int which = blockIdx.y;
    const float* src; f16* dst; int count;
    if (which == 0)      { src = Wq; dst = whq; count = 64 * 512; }
    else if (which == 1) { src = Wk; dst = whk; count = 64 * 512; }
    else                 { src = Wv; dst = whv; count = 512 * 512; }
    const int i = (blockIdx.x * 256 + threadIdx.x) * 4;
    if (i < count) {
        const float4 v4 = *(const float4*)(src + i);
        f16x4 o;
        o[0] = (f16)v4.x; o[1] = (f16)v4.y; o[2] = (f16)v4.z; o[3] = (f16)v4.w;
        *(f16x4*)(dst + i) = o;
    }
}

// ---------------------------------------------------------------------------
// Fused projection: virtual weight [Wq;Wk;Wv] (640 rows) x xT.
// grid (18 n-tiles(128), 5 row-tiles(128), 16 b), block 256.
// Epilogue: LDS transpose so ALL global stores are coalesced 16 B. q rows
// pre-scaled by log2e so attn can use raw v_exp_f32.
// ---------------------------------------------------------------------------
__global__ __launch_bounds__(256, 2) void proj_kernel(
    const f16* __restrict__ xT, const f16* __restrict__ whq,
    const f16* __restrict__ whk, const f16* __restrict__ whv,
    f16* __restrict__ qTo, f16* __restrict__ kTo,
    unsigned short* __restrict__ vout)
{
    const int nt = blockIdx.x;
    const int rt = blockIdx.y;
    const int b  = blockIdx.z;
    const int t  = threadIdx.x;
    const int wave = t >> 6, lane = t & 63;
    const int row = lane & 31, lh = lane >> 5;

    // unified LDS: main loop uses two [128][72] f16 tiles; epilogue reuses as
    // a [128][130] u16 transpose buffer (33,280 B <= 36,864 B).
    __shared__ f16 smem[2 * 128 * 72];
    f16 (*wsm)[72] = (f16(*)[72])smem;
    f16 (*xs)[72]  = (f16(*)[72])(smem + 128 * 72);

    f32x16 acc[4];
    #pragma unroll
    for (int s = 0; s < 4; ++s)
        #pragma unroll
        for (int r = 0; r < 16; ++r) acc[s][r] = 0.0f;

    for (int c0 = 0; c0 < CHN; c0 += 64) {
        __syncthreads();
        #pragma unroll
        for (int r = 0; r < 4; ++r) {
            const int id = t + r * 256;     // 1024 8-elem chunks
            const int co = id >> 3, cg = id & 7;
            const f16* src;
            if (rt == 0) src = (co < 64) ? (whq + (size_t)co * CHN)
                                         : (whk + (size_t)(co - 64) * CHN);
            else         src = whv + (size_t)((rt - 1) * 128 + co) * CHN;
            *(f16x8*)&wsm[co][cg * 8] = *(const f16x8*)(src + c0 + cg * 8);
        }
        #pragma unroll
        for (int r = 0; r < 4; ++r) {
            const int id = t + r * 256;
            const int n = id >> 3, cg = id & 7;
            *(f16x8*)&xs[n][cg * 8] =
                *(const f16x8*)(xT + ((size_t)b * NPIX + (size_t)(nt * 128 + n)) * CHN + c0 + cg * 8);
        }
        __syncthreads();

        #pragma unroll
        for (int kk = 0; kk < 64; kk += 16) {
            const f16x8 bf = *(const f16x8*)&xs[wave * 32 + row][kk + lh * 8];
            #pragma unroll
            for (int cs = 0; cs < 4; ++cs) {
                const f16x8 af = *(const f16x8*)&wsm[cs * 32 + row][kk + lh * 8];
                acc[cs] = __builtin_amdgcn_mfma_f32_32x32x16_f16(af, bf, acc[cs], 0, 0, 0);
            }
        }
    }

    // ---- epilogue via LDS transpose (row stride 130 u16: conflict-free) ----
    __syncthreads();
    unsigned short* eb = (unsigned short*)smem;   // [128][130]
    const int nl = wave * 32 + row;

    if (rt == 0) {
        #pragma unroll
        for (int cs = 0; cs < 4; ++cs) {
            const float sc = (cs < 2) ? LOG2E : 1.0f;
            #pragma unroll
            for (int tp = 0; tp < 8; ++tp) {
                const int r = tp * 2;
                const int i = cs * 32 + (r & 3) + 8 * (r >> 2) + 4 * lh;  // even
                *(unsigned*)&eb[nl * 130 + i] =
                    pack_f16(acc[cs][r] * sc, acc[cs][r + 1] * sc);
            }
        }
    } else {
        #pragma unroll
        for (int cs = 0; cs < 4; ++cs)
            #pragma unroll
            for (int r = 0; r < 16; ++r) {
                const int cl = cs * 32 + (r & 3) + 8 * (r >> 2) + 4 * lh;
                eb[cl * 130 + nl] = f2bf(acc[cs][r]);
            }
    }
    __syncthreads();

    #pragma unroll
    for (int u = 0; u < 8; ++u) {
        const int id = t + u * 256;
        const int rr = id >> 4;
        const int ch = id & 15;
        const unsigned short* src = &eb[rr * 130 + ch * 8];
        s16x8 w;
        #pragma unroll
        for (int k = 0; k < 4; ++k)
            ((unsigned*)&w)[k] = *(const unsigned*)(src + k * 2);
        if (rt == 0) {
            f16* dst = (ch < 8)
                ? (qTo + ((size_t)b * NPIX + nt * 128 + rr) * INTER + ch * 8)
                : (kTo + ((size_t)b * NPIX + nt * 128 + rr) * INTER + (ch - 8) * 8);
            *(s16x8*)dst = w;
        } else {
            *(s16x8*)(vout + ((size_t)b * CHN + (size_t)((rt - 1) * 128 + rr)) * NPIX
                      + nt * 128 + ch * 8) = w;
        }
    }
}

// ---------------------------------------------------------------------------
// Attention v13: v12's register diet with the cvtpk gamble REVERTED.
// v12 failed correctness (absmax 8.05); the only functional delta vs the
// passing v8 was v_cvt_pk_bf16_f32 — its gfx950 semantics differ from
// assumed. v13 restores the HW-proven pack_bf16 (bit-identical P to v8)
// and keeps the structural diet:
//  - last iteration PEELED (no dummy loads, no per-iter m1 select)
//  - loop-carried DMA src pointers (vsrc += 128 B, ksrc += 8 KB per iter)
//  - incremental pack+swap (4 live temps, not 8)
// Goal: fit launch_bounds(256,4) = 128 unified regs -> 4 waves/SIMD,
// 16 waves/CU, 4 blocks x 40,960 B = 163,840 B LDS (exact CU pool).
// Rationale: v8/v10/v11 all ~182 us with Occ <=25% -> issue/latency-bound
// at 2-3 waves/SIMD; occupancy is the only untried lever.
// Spill canary: WRITE_SIZE >> 80 MB (v7 lesson).
// ---------------------------------------------------------------------------
__global__ __launch_bounds__(256, 4) void attn_kernel(
    const float* __restrict__ x, const float* __restrict__ gamma,
    const f16* __restrict__ qT, const f16* __restrict__ kT,
    const unsigned short* __restrict__ vglob, float* __restrict__ out)
{
    const int nt = blockIdx.x;    // 128-n tile
    const int cq = blockIdx.y;    // 128-c quarter
    const int b  = blockIdx.z;
    const int t  = threadIdx.x;
    const int wave = t >> 6, lane = t & 63;
    const int row = lane & 31, lh = lane >> 5;

    __shared__ short vbuf[2][128 * 64];   // [buf][c][m] chunk-swizzled, 32 KB
    __shared__ f16   kbuf[64 * 64];       // [m][i] chunk-swizzled, 8 KB (single)

    // gload_lds staging ids: lane l covers row (8*wave + l>>3), chunk l&7.
    const int lrow = lane >> 3;
    const int lch  = lane & 7;
    const int xorv = row & 7;      // fragment-read chunk swizzle

    // loop-carried per-lane DMA source pointers
    const unsigned short* vsrc[4];
    const f16* ksrc[2];
    {
        const unsigned short* vq = vglob + ((size_t)b * CHN + (size_t)cq * 128) * NPIX;
        const f16* kb = kT + (size_t)b * NPIX * INTER;
        #pragma unroll
        for (int j = 0; j < 4; ++j) {
            const int r = j * 32 + wave * 8 + lrow;
            vsrc[j] = vq + (size_t)r * NPIX + ((lch ^ (r & 7)) * 8);
        }
        #pragma unroll
        for (int j = 0; j < 2; ++j) {
            const int r = j * 32 + wave * 8 + lrow;
            ksrc[j] = kb + (size_t)r * INTER + ((lch ^ (r & 7)) * 8);
        }
    }

    // q fragments: resident (B operand; col n = lane&31); wave owns 32 n
    f16x8 qf[4];
    {
        const f16* qrow = qT + ((size_t)b * NPIX
                          + (size_t)(nt * 128 + wave * 32 + row)) * INTER + lh * 8;
        #pragma unroll
        for (int k0 = 0; k0 < 4; ++k0) qf[k0] = *(const f16x8*)(qrow + k0 * 16);
    }

    // ---- prologue: stage tile 0 (async, drained by the syncthreads)
    #pragma unroll
    for (int j = 0; j < 4; ++j) {
        gload_lds16(vsrc[j], &vbuf[0][(j * 32 + wave * 8) * 64]);
        vsrc[j] += 64;                       // next m-tile (+128 B)
    }
    #pragma unroll
    for (int j = 0; j < 2; ++j) {
        gload_lds16(ksrc[j], &kbuf[(j * 32 + wave * 8) * 64]);
        ksrc[j] += 64 * INTER;               // next 64 m-rows (+8 KB)
    }
    __syncthreads();

    f32x16 accv[4];   // [cs] : (32 c) x (this wave's 32 n) — 64 AGPR
    #pragma unroll
    for (int s = 0; s < 4; ++s)
        #pragma unroll
        for (int r = 0; r < 16; ++r) accv[s][r] = 0.0f;

    float lrun = 0.0f;
    union PB { unsigned u[4]; s16x8 v; };

    #pragma unroll 1
    for (int it = 0; it < NPIX / 64 - 1; ++it) {   // 35 staged iters; last peeled
        const int cur = it & 1, nxt = cur ^ 1;

        // ---- issue async v-stage for tile it+1 -> vbuf[nxt] (spans QK+exp)
        #pragma unroll
        for (int j = 0; j < 4; ++j) {
            gload_lds16(vsrc[j], &vbuf[nxt][(j * 32 + wave * 8) * 64]);
            vsrc[j] += 64;
        }

        // ---- QK^T both m-halves for this wave's 32 n; exp2 + pack + swap
        union PB pb[4];   // [kk] : P B-operand, m-chunk kk*16
        #pragma unroll
        for (int mh = 0; mh < 2; ++mh) {
            f32x16 sacc;
            #pragma unroll
            for (int r = 0; r < 16; ++r) sacc[r] = 0.0f;
            #pragma unroll
            for (int k0 = 0; k0 < 4; ++k0) {
                const f16x8 af = *(const f16x8*)&kbuf[(mh * 32 + row) * 64
                                    + (((k0 * 2 + lh) ^ xorv) * 8)];
                sacc = __builtin_amdgcn_mfma_f32_32x32x16_f16(af, qf[k0], sacc, 0, 0, 0);
            }
            #pragma unroll
            for (int half = 0; half < 2; ++half) {
                unsigned pg[4];
                #pragma unroll
                for (int j = 0; j < 4; ++j) {
                    const int tt = half * 4 + j;
                    const float p0 = exp2_fast(sacc[2 * tt + 0]);
                    const float p1 = exp2_fast(sacc[2 * tt + 1]);
                    lrun += p0 + p1;
                    pg[j] = pack_bf16(p0, p1);
                }
                unsigned nx, ny;
                swap32(pg[0], pg[2], nx, ny, lh);
                pb[2 * mh + half].u[0] = nx;
                pb[2 * mh + half].u[2] = ny;
                swap32(pg[1], pg[3], nx, ny, lh);
                pb[2 * mh + half].u[1] = nx;
                pb[2 * mh + half].u[3] = ny;
            }
        }

        // ---- barrier A: kbuf QK reads done; v-stage drained (QK covered it)
        __syncthreads();

        // ---- issue async k-stage for tile it+1 -> kbuf (spans PV)
        #pragma unroll
        for (int j = 0; j < 2; ++j) {
            gload_lds16(ksrc[j], &kbuf[(j * 32 + wave * 8) * 64]);
            ksrc[j] += 64 * INTER;
        }

        // ---- PV: A = v-frags from LDS (full 128 c), B = pb regs
        #pragma unroll
        for (int cs = 0; cs < 4; ++cs)
            #pragma unroll
            for (int kk = 0; kk < 4; ++kk) {
                const s16x8 va = *(const s16x8*)&vbuf[cur][(cs * 32 + row) * 64
                                    + (((kk * 2 + lh) ^ xorv) * 8)];
                accv[cs] = __builtin_amdgcn_mfma_f32_32x32x16_bf16(
                    va, pb[kk].v, accv[cs], 0, 0, 0);
            }

        // ---- barrier B: k-stage drained; staged tile visible for next iter
        __syncthreads();
    }

    // ---- peeled final iteration (tile 35 resident in vbuf[1] / kbuf)
    {
        const int cur = (NPIX / 64 - 1) & 1;   // = 1
        union PB pb[4];
        #pragma unroll
        for (int mh = 0; mh < 2; ++mh) {
            f32x16 sacc;
            #pragma unroll
            for (int r = 0; r < 16; ++r) sacc[r] = 0.0f;
            #pragma unroll
            for (int k0 = 0; k0 < 4; ++k0) {
                const f16x8 af = *(const f16x8*)&kbuf[(mh * 32 + row) * 64
                                    + (((k0 * 2 + lh) ^ xorv) * 8)];
                sacc = __builtin_amdgcn_mfma_f32_32x32x16_f16(af, qf[k0], sacc, 0, 0, 0);
            }
            #pragma unroll
            for (int half = 0; half < 2; ++half) {
                unsigned pg[4];
                #pragma unroll
                for (int j = 0; j < 4; ++j) {
                    const int tt = half * 4 + j;
                    const float p0 = exp2_fast(sacc[2 * tt + 0]);
                    const float p1 = exp2_fast(sacc[2 * tt + 1]);
                    lrun += p0 + p1;
                    pg[j] = pack_bf16(p0, p1);
                }
                unsigned nx, ny;
                swap32(pg[0], pg[2], nx, ny, lh);
                pb[2 * mh + half].u[0] = nx;
                pb[2 * mh + half].u[2] = ny;
                swap32(pg[1], pg[3], nx, ny, lh);
                pb[2 * mh + half].u[1] = nx;
                pb[2 * mh + half].u[3] = ny;
            }
        }
        #pragma unroll
        for (int cs = 0; cs < 4; ++cs)
            #pragma unroll
            for (int kk = 0; kk < 4; ++kk) {
                const s16x8 va = *(const s16x8*)&vbuf[cur][(cs * 32 + row) * 64
                                    + (((kk * 2 + lh) ^ xorv) * 8)];
                accv[cs] = __builtin_amdgcn_mfma_f32_32x32x16_bf16(
                    va, pb[kk].v, accv[cs], 0, 0, 0);
            }
    }

    // ---- epilogue: l combine (lane-half pair covers all 64 m), out = g*acc/l + x
    const float g = gamma[0];
    const float linv = 1.0f / (lrun + __shfl_xor(lrun, 32, 64));
    const int n = nt * 128 + wave * 32 + row;

    #pragma unroll
    for (int cs = 0; cs < 4; ++cs)
        #pragma unroll
        for (int r = 0; r < 16; ++r) {
            const int c = cq * 128 + cs * 32 + (r & 3) + 8 * (r >> 2) + 4 * lh;
            const size_t idx = ((size_t)b * CHN + c) * NPIX + n;
            out[idx] = g * accv[cs][r] * linv + x[idx];
        }
}

// ---------------------------------------------------------------------------
extern "C" void kernel_launch(void* const* d_in, const int* in_sizes, int n_in,
                              void* d_out, int out_size, void* d_ws, size_t ws_size,
                              hipStream_t stream) {
    (void)in_sizes; (void)n_in; (void)out_size; (void)ws_size;
    const float* x     = (const float*)d_in[0];
    const float* Wq    = (const float*)d_in[1];
    const float* Wk    = (const float*)d_in[2];
    const float* Wv    = (const float*)d_in[3];
    const float* gamma = (const float*)d_in[4];
    float* out = (float*)d_out;
    char* ws = (char*)d_ws;

    f16* xT  = (f16*)(ws + XT_OFF);
    f16* qTp = (f16*)(ws + QT_OFF);
    f16* kTp = (f16*)(ws + KT_OFF);
    unsigned short* vb = (unsigned short*)(ws + VB_OFF);
    f16* whq = (f16*)(ws + WHQ_OFF);
    f16* whk = (f16*)(ws + WHK_OFF);
    f16* whv = (f16*)(ws + WHV_OFF);

    convert_x_kernel<<<dim3(36, 8, 16), 256, 0, stream>>>(x, xT);
    convert_w_kernel<<<dim3(256, 3, 1), 256, 0, stream>>>(Wq, Wk, Wv, whq, whk, whv);
    proj_kernel<<<dim3(18, 5, 16), 256, 0, stream>>>(xT, whq, whk, whv, qTp, kTp, vb);
    attn_kernel<<<dim3(18, 4, 16), 256, 0, stream>>>(x, gamma, qTp, kTp, vb, out);
}

// Round 17
// 350.910 us; speedup vs baseline: 1.1167x; 1.1167x over previous
//
#include <hip/hip_runtime.h>

#define BATCH 16
#define CHN   512
#define INTER 64
#define NPIX  2304   // 48*48

typedef _Float16 f16;
typedef _Float16 f16x8 __attribute__((ext_vector_type(8)));
typedef _Float16 f16x4 __attribute__((ext_vector_type(4)));
typedef short    s16x8 __attribute__((ext_vector_type(8)));
typedef float    f32x16 __attribute__((ext_vector_type(16)));

// workspace byte offsets (total 85,590,016 B)
#define XT_OFF   ((size_t)0)          // xT f16  [b][n][c]   16*2304*512
#define QT_OFF   ((size_t)37748736)   // qT f16  [b][n][64]  (pre-scaled by log2e)
#define KT_OFF   ((size_t)42467328)   // kT f16  [b][n][64]
#define VB_OFF   ((size_t)47185920)   // v  bf16 [b][c][m]   16*512*2304
#define WHQ_OFF  ((size_t)84934656)   // Wq f16  [64][512]
#define WHK_OFF  ((size_t)85000192)   // Wk f16  [64][512]
#define WHV_OFF  ((size_t)85065728)   // Wv f16  [512][512]

#define LOG2E 1.4426950408889634f

__device__ inline unsigned short f2bf(float f) {
    unsigned int u = __float_as_uint(f);
    unsigned int r = (u + 0x7FFFu + ((u >> 16) & 1u)) >> 16;
    return (unsigned short)r;
}

// pack two fp32 -> (bf16(a) | bf16(b)<<16), round-half-up via +0x8000 then
// v_perm. HW-PROVEN (351.8 us run). v12's v_cvt_pk_bf16_f32 FAILED (absmax
// 8.05) — do not reintroduce without isolated HW verification.
__device__ inline unsigned pack_bf16(float a, float b) {
    unsigned ua = __float_as_uint(a) + 0x8000u;
    unsigned ub = __float_as_uint(b) + 0x8000u;
    return __builtin_amdgcn_perm(ub, ua, 0x07060302u);
}

// pack two fp32 -> two f16 in one u32
__device__ inline unsigned pack_f16(float a, float b) {
    f16 ha = (f16)a, hb = (f16)b;
    unsigned short ua = *(unsigned short*)&ha, ub = *(unsigned short*)&hb;
    return (unsigned)ua | ((unsigned)ub << 16);
}

// 2^x via v_exp_f32
__device__ inline float exp2_fast(float x) {
#if __has_builtin(__builtin_amdgcn_exp2f)
    return __builtin_amdgcn_exp2f(x);
#else
    float r; asm("v_exp_f32 %0, %1" : "=v"(r) : "v"(x)); return r;
#endif
}

// async global->LDS, 16 B per lane; lane l lands at base + l*16.
__device__ inline void gload_lds16(const void* g, void* l) {
    __builtin_amdgcn_global_load_lds(
        (const __attribute__((address_space(1))) void*)g,
        (__attribute__((address_space(3))) void*)l, 16, 0, 0);
}

// Lane-half swap between two VGPRs (HW-verified).
__device__ inline void swap32(unsigned x, unsigned y, unsigned& nx, unsigned& ny, int lh) {
#if __has_builtin(__builtin_amdgcn_permlane32_swap)
    auto r = __builtin_amdgcn_permlane32_swap(x, y, false, false);
    nx = r[0]; ny = r[1];
#else
    const unsigned xs = (unsigned)__shfl_xor((int)x, 32, 64);
    const unsigned ys = (unsigned)__shfl_xor((int)y, 32, 64);
    nx = lh ? ys : x;
    ny = lh ? y  : xs;
#endif
}

// ---------------------------------------------------------------------------
// x [b][c][n] fp32  ->  xT [b][n][c] f16   (64x64 LDS tile transpose)
// ---------------------------------------------------------------------------
__global__ __launch_bounds__(256) void convert_x_kernel(
    const float* __restrict__ x, f16* __restrict__ xT)
{
    const int n0 = blockIdx.x * 64;
    const int c0 = blockIdx.y * 64;
    const int b  = blockIdx.z;
    const int t  = threadIdx.x;

    __shared__ float tile[64][65];

    {
        const int cr   = t >> 2;
        const int ncol = (t & 3) * 16;
        const float* src = x + ((size_t)b * CHN + (size_t)(c0 + cr)) * NPIX + n0 + ncol;
        #pragma unroll
        for (int u = 0; u < 4; ++u) {
            const float4 v4 = *(const float4*)(src + u * 4);
            tile[cr][ncol + u * 4 + 0] = v4.x;
            tile[cr][ncol + u * 4 + 1] = v4.y;
            tile[cr][ncol + u * 4 + 2] = v4.z;
            tile[cr][ncol + u * 4 + 3] = v4.w;
        }
    }
    __syncthreads();
    #pragma unroll
    for (int r = 0; r < 2; ++r) {
        const int id = t + r * 256;
        const int n  = id >> 3;
        const int cg = id & 7;
        f16x8 o;
        #pragma unroll
        for (int j = 0; j < 8; ++j) o[j] = (f16)tile[cg * 8 + j][n];
        *(f16x8*)(xT + ((size_t)b * NPIX + (size_t)(n0 + n)) * CHN + c0 + cg * 8) = o;
    }
}

// ---------------------------------------------------------------------------
// W fp32 -> f16. grid (256, 3), block 256.
// ---------------------------------------------------------------------------
__global__ __launch_bounds__(256) void convert_w_kernel(
    const float* __restrict__ Wq, const float* __restrict__ Wk,
    const float* __restrict__ Wv, f16* __restrict__ whq,
    f16* __restrict__ whk, f16* __restrict__ whv)
{
    const int which = blockIdx.y;
    const float* src; f16* dst; int count;
    if (which == 0)      { src = Wq; dst = whq; count = 64 * 512; }
    else if (which == 1) { src = Wk; dst = whk; count = 64 * 512; }
    else                 { src = Wv; dst = whv; count = 512 * 512; }
    const int i = (blockIdx.x * 256 + threadIdx.x) * 4;
    if (i < count) {
        const float4 v4 = *(const float4*)(src + i);
        f16x4 o;
        o[0] = (f16)v4.x; o[1] = (f16)v4.y; o[2] = (f16)v4.z; o[3] = (f16)v4.w;
        *(f16x4*)(dst + i) = o;
    }
}

// ---------------------------------------------------------------------------
// Fused projection: virtual weight [Wq;Wk;Wv] (640 rows) x xT.
// FLAT grid 1440 = rt(5) x b(16) x nt(18), decoded rt = bid/288 so the 5
// rt-blocks sharing one xT panel (2.36 MB < 4 MB L2) have bid stride 288
// (== 0 mod 8) -> SAME XCD under round-robin dispatch -> panel is fetched
// once per XCD and re-read from L2 (xT L3/HBM traffic ~5x down).
// launch_bounds(256,4): unified ~114 (64 AGPR + ~50 arch) <= 128 -> 4
// blocks/CU (LDS 4 x 36,864 = 147,456 <= 163,840) — doubles latency hiding
// in this latency/BW-bound kernel. Epilogue unchanged (coalesced 16 B
// stores; q pre-scaled by log2e).
// ---------------------------------------------------------------------------
__global__ __launch_bounds__(256, 4) void proj_kernel(
    const f16* __restrict__ xT, const f16* __restrict__ whq,
    const f16* __restrict__ whk, const f16* __restrict__ whv,
    f16* __restrict__ qTo, f16* __restrict__ kTo,
    unsigned short* __restrict__ vout)
{
    const int bid = blockIdx.x;
    const int rt  = bid / 288;            // 0..4
    const int rem = bid - rt * 288;
    const int b   = rem / 18;             // 0..15
    const int nt  = rem - b * 18;         // 0..17
    const int t  = threadIdx.x;
    const int wave = t >> 6, lane = t & 63;
    const int row = lane & 31, lh = lane >> 5;

    // unified LDS: main loop uses two [128][72] f16 tiles; epilogue reuses as
    // a [128][130] u16 transpose buffer (33,280 B <= 36,864 B).
    __shared__ f16 smem[2 * 128 * 72];
    f16 (*wsm)[72] = (f16(*)[72])smem;
    f16 (*xs)[72]  = (f16(*)[72])(smem + 128 * 72);

    f32x16 acc[4];
    #pragma unroll
    for (int s = 0; s < 4; ++s)
        #pragma unroll
        for (int r = 0; r < 16; ++r) acc[s][r] = 0.0f;

    for (int c0 = 0; c0 < CHN; c0 += 64) {
        __syncthreads();
        #pragma unroll
        for (int r = 0; r < 4; ++r) {
            const int id = t + r * 256;     // 1024 8-elem chunks
            const int co = id >> 3, cg = id & 7;
            const f16* src;
            if (rt == 0) src = (co < 64) ? (whq + (size_t)co * CHN)
                                         : (whk + (size_t)(co - 64) * CHN);
            else         src = whv + (size_t)((rt - 1) * 128 + co) * CHN;
            *(f16x8*)&wsm[co][cg * 8] = *(const f16x8*)(src + c0 + cg * 8);
        }
        #pragma unroll
        for (int r = 0; r < 4; ++r) {
            const int id = t + r * 256;
            const int n = id >> 3, cg = id & 7;
            *(f16x8*)&xs[n][cg * 8] =
                *(const f16x8*)(xT + ((size_t)b * NPIX + (size_t)(nt * 128 + n)) * CHN + c0 + cg * 8);
        }
        __syncthreads();

        #pragma unroll
        for (int kk = 0; kk < 64; kk += 16) {
            const f16x8 bf = *(const f16x8*)&xs[wave * 32 + row][kk + lh * 8];
            #pragma unroll
            for (int cs = 0; cs < 4; ++cs) {
                const f16x8 af = *(const f16x8*)&wsm[cs * 32 + row][kk + lh * 8];
                acc[cs] = __builtin_amdgcn_mfma_f32_32x32x16_f16(af, bf, acc[cs], 0, 0, 0);
            }
        }
    }

    // ---- epilogue via LDS transpose (row stride 130 u16: conflict-free) ----
    __syncthreads();
    unsigned short* eb = (unsigned short*)smem;   // [128][130]
    const int nl = wave * 32 + row;

    if (rt == 0) {
        #pragma unroll
        for (int cs = 0; cs < 4; ++cs) {
            const float sc = (cs < 2) ? LOG2E : 1.0f;
            #pragma unroll
            for (int tp = 0; tp < 8; ++tp) {
                const int r = tp * 2;
                const int i = cs * 32 + (r & 3) + 8 * (r >> 2) + 4 * lh;  // even
                *(unsigned*)&eb[nl * 130 + i] =
                    pack_f16(acc[cs][r] * sc, acc[cs][r + 1] * sc);
            }
        }
    } else {
        #pragma unroll
        for (int cs = 0; cs < 4; ++cs)
            #pragma unroll
            for (int r = 0; r < 16; ++r) {
                const int cl = cs * 32 + (r & 3) + 8 * (r >> 2) + 4 * lh;
                eb[cl * 130 + nl] = f2bf(acc[cs][r]);
            }
    }
    __syncthreads();

    #pragma unroll
    for (int u = 0; u < 8; ++u) {
        const int id = t + u * 256;
        const int rr = id >> 4;
        const int ch = id & 15;
        const unsigned short* src = &eb[rr * 130 + ch * 8];
        s16x8 w;
        #pragma unroll
        for (int k = 0; k < 4; ++k)
            ((unsigned*)&w)[k] = *(const unsigned*)(src + k * 2);
        if (rt == 0) {
            f16* dst = (ch < 8)
                ? (qTo + ((size_t)b * NPIX + nt * 128 + rr) * INTER + ch * 8)
                : (kTo + ((size_t)b * NPIX + nt * 128 + rr) * INTER + (ch - 8) * 8);
            *(s16x8*)dst = w;
        } else {
            *(s16x8*)(vout + ((size_t)b * CHN + (size_t)((rt - 1) * 128 + rr)) * NPIX
                      + nt * 128 + ch * 8) = w;
        }
    }
}

// ---------------------------------------------------------------------------
// Attention v8 (EXACT revert — best verified config, 177 us / 351.8 total).
// Four rounds of evidence: schedule variants (v10 1-barrier, v11 counted
// vmcnt) = null; cq=2 redundancy cut (v9) = wash; occupancy push (v13
// 128-reg diet) = negative via forced-cap spill. ~177 us is this
// structure's floor; do not perturb without a new mechanism.
// ---------------------------------------------------------------------------
__global__ __launch_bounds__(256, 3) void attn_kernel(
    const float* __restrict__ x, const float* __restrict__ gamma,
    const f16* __restrict__ qT, const f16* __restrict__ kT,
    const unsigned short* __restrict__ vglob, float* __restrict__ out)
{
    const int nt = blockIdx.x;    // 128-n tile
    const int cq = blockIdx.y;    // 128-c quarter
    const int b  = blockIdx.z;
    const int t  = threadIdx.x;
    const int wave = t >> 6, lane = t & 63;
    const int row = lane & 31, lh = lane >> 5;

    __shared__ short vbuf[2][128 * 64];   // [buf][c][m] chunk-swizzled, 32 KB
    __shared__ f16   kbuf[64 * 64];       // [m][i] chunk-swizzled, 8 KB (single)

    const unsigned short* vq = vglob + ((size_t)b * CHN + (size_t)cq * 128) * NPIX;
    const f16* kb = kT + (size_t)b * NPIX * INTER;

    // gload_lds staging ids: lane l covers row (8*wave + l>>3), chunk l&7.
    const int lrow = lane >> 3;    // 0..7 within wave's 8-row group
    const int lch  = lane & 7;

    const int xorv = row & 7;      // fragment-read chunk swizzle

    // q fragments: resident (B operand; col n = lane&31); wave owns 32 n
    f16x8 qf[4];
    {
        const f16* qrow = qT + ((size_t)b * NPIX
                          + (size_t)(nt * 128 + wave * 32 + row)) * INTER + lh * 8;
        #pragma unroll
        for (int k0 = 0; k0 < 4; ++k0) qf[k0] = *(const f16x8*)(qrow + k0 * 16);
    }

    // ---- prologue: stage tile 0 (async, drained by the syncthreads)
    #pragma unroll
    for (int j = 0; j < 4; ++j) {
        const int r = j * 32 + wave * 8 + lrow;          // v c-row 0..127
        gload_lds16(vq + (size_t)r * NPIX + ((lch ^ (r & 7)) * 8),
                    &vbuf[0][(j * 32 + wave * 8) * 64]);
    }
    #pragma unroll
    for (int j = 0; j < 2; ++j) {
        const int r = j * 32 + wave * 8 + lrow;          // k m-row 0..63
        gload_lds16(kb + (size_t)r * INTER + ((lch ^ (r & 7)) * 8),
                    &kbuf[(j * 32 + wave * 8) * 64]);
    }
    __syncthreads();

    f32x16 accv[4];   // [cs] : (32 c) x (this wave's 32 n)
    #pragma unroll
    for (int s = 0; s < 4; ++s)
        #pragma unroll
        for (int r = 0; r < 16; ++r) accv[s][r] = 0.0f;

    float lrun = 0.0f;
    union PB { unsigned u[4]; s16x8 v; };

    for (int it = 0; it < NPIX / 64; ++it) {
        const int cur = it & 1, nxt = cur ^ 1;
        const int m1 = (it < NPIX / 64 - 1) ? (it + 1) * 64 : 0;  // last: dummy reload

        // ---- issue async v-stage for tile it+1 -> vbuf[nxt] (spans QK+exp)
        #pragma unroll
        for (int j = 0; j < 4; ++j) {
            const int r = j * 32 + wave * 8 + lrow;
            gload_lds16(vq + (size_t)r * NPIX + m1 + ((lch ^ (r & 7)) * 8),
                        &vbuf[nxt][(j * 32 + wave * 8) * 64]);
        }

        // ---- QK^T both m-halves for this wave's 32 n; exp2 + pack + transform
        union PB pb[4];   // [kk] : P B-operand, m-chunk kk*16
        #pragma unroll
        for (int mh = 0; mh < 2; ++mh) {
            f32x16 sacc;
            #pragma unroll
            for (int r = 0; r < 16; ++r) sacc[r] = 0.0f;
            #pragma unroll
            for (int k0 = 0; k0 < 4; ++k0) {
                const f16x8 af = *(const f16x8*)&kbuf[(mh * 32 + row) * 64
                                    + (((k0 * 2 + lh) ^ xorv) * 8)];
                sacc = __builtin_amdgcn_mfma_f32_32x32x16_f16(af, qf[k0], sacc, 0, 0, 0);
            }
            float lp = 0.0f;
            unsigned pg[8];
            #pragma unroll
            for (int tt = 0; tt < 8; ++tt) {
                const float p0 = exp2_fast(sacc[2 * tt + 0]);
                const float p1 = exp2_fast(sacc[2 * tt + 1]);
                lp += p0 + p1;
                pg[tt] = pack_bf16(p0, p1);
            }
            lrun += lp;
            #pragma unroll
            for (int half = 0; half < 2; ++half)
                #pragma unroll
                for (int p = 0; p < 2; ++p) {
                    unsigned nx, ny;
                    swap32(pg[half * 4 + p], pg[half * 4 + 2 + p], nx, ny, lh);
                    pb[2 * mh + half].u[p]     = nx;
                    pb[2 * mh + half].u[p + 2] = ny;
                }
        }

        // ---- barrier A: kbuf QK reads done; v-stage drained (had QK to cover)
        __syncthreads();

        // ---- issue async k-stage for tile it+1 -> kbuf (spans PV)
        #pragma unroll
        for (int j = 0; j < 2; ++j) {
            const int r = j * 32 + wave * 8 + lrow;
            gload_lds16(kb + (size_t)(m1 + r) * INTER + ((lch ^ (r & 7)) * 8),
                        &kbuf[(j * 32 + wave * 8) * 64]);
        }

        // ---- PV: A = v-frags from LDS (full 128 c), B = pb regs
        #pragma unroll
        for (int cs = 0; cs < 4; ++cs)
            #pragma unroll
            for (int kk = 0; kk < 4; ++kk) {
                const s16x8 va = *(const s16x8*)&vbuf[cur][(cs * 32 + row) * 64
                                    + (((kk * 2 + lh) ^ xorv) * 8)];
                accv[cs] = __builtin_amdgcn_mfma_f32_32x32x16_bf16(
                    va, pb[kk].v, accv[cs], 0, 0, 0);
            }

        // ---- barrier B: k-stage drained; staged tile visible for next iter
        __syncthreads();
    }

    // ---- epilogue: l combine (lane-half pair covers all 64 m), out = g*acc/l + x
    const float g = gamma[0];
    const float linv = 1.0f / (lrun + __shfl_xor(lrun, 32, 64));
    const int n = nt * 128 + wave * 32 + row;

    #pragma unroll
    for (int cs = 0; cs < 4; ++cs)
        #pragma unroll
        for (int r = 0; r < 16; ++r) {
            const int c = cq * 128 + cs * 32 + (r & 3) + 8 * (r >> 2) + 4 * lh;
            const size_t idx = ((size_t)b * CHN + c) * NPIX + n;
            out[idx] = g * accv[cs][r] * linv + x[idx];
        }
}

// ---------------------------------------------------------------------------
extern "C" void kernel_launch(void* const* d_in, const int* in_sizes, int n_in,
                              void* d_out, int out_size, void* d_ws, size_t ws_size,
                              hipStream_t stream) {
    (void)in_sizes; (void)n_in; (void)out_size; (void)ws_size;
    const float* x     = (const float*)d_in[0];
    const float* Wq    = (const float*)d_in[1];
    const float* Wk    = (const float*)d_in[2];
    const float* Wv    = (const float*)d_in[3];
    const float* gamma = (const float*)d_in[4];
    float* out = (float*)d_out;
    char* ws = (char*)d_ws;

    f16* xT  = (f16*)(ws + XT_OFF);
    f16* qTp = (f16*)(ws + QT_OFF);
    f16* kTp = (f16*)(ws + KT_OFF);
    unsigned short* vb = (unsigned short*)(ws + VB_OFF);
    f16* whq = (f16*)(ws + WHQ_OFF);
    f16* whk = (f16*)(ws + WHK_OFF);
    f16* whv = (f16*)(ws + WHV_OFF);

    convert_x_kernel<<<dim3(36, 8, 16), 256, 0, stream>>>(x, xT);
    convert_w_kernel<<<dim3(256, 3, 1), 256, 0, stream>>>(Wq, Wk, Wv, whq, whk, whv);
    proj_kernel<<<dim3(1440, 1, 1), 256, 0, stream>>>(xT, whq, whk, whv, qTp, kTp, vb);
    attn_kernel<<<dim3(18, 4, 16), 256, 0, stream>>>(x, gamma, qTp, kTp, vb, out);
}